// Round 2
// baseline (636.615 us; speedup 1.0000x reference)
//
#include <hip/hip_runtime.h>

#define NNODES 100000
#define NEDGES 800000
#define D 128
#define NB1 391  // ceil(NNODES/256)

// ---------------- CSR build ----------------

__global__ __launch_bounds__(256) void k_count(const int* __restrict__ ei,
                                               int* __restrict__ cnt) {
    int e = blockIdx.x * 256 + threadIdx.x;          // grid sized exactly E/256
    atomicAdd(&cnt[ei[e]], 1);
}

__global__ __launch_bounds__(256) void k_scan1(const int* __restrict__ cnt,
                                               int* __restrict__ off,
                                               int* __restrict__ bsum) {
    __shared__ int s[256];
    int t = threadIdx.x;
    int i = blockIdx.x * 256 + t;
    int v = (i < NNODES) ? cnt[i] : 0;
    s[t] = v;
    __syncthreads();
    for (int d = 1; d < 256; d <<= 1) {
        int a = (t >= d) ? s[t - d] : 0;
        __syncthreads();
        s[t] += a;
        __syncthreads();
    }
    if (i < NNODES) off[i] = s[t] - v;               // exclusive within block
    if (t == 255) bsum[blockIdx.x] = s[255];         // block total
}

__global__ __launch_bounds__(512) void k_scan2(int* __restrict__ bsum) {
    __shared__ int s[512];
    int t = threadIdx.x;
    int v = (t < NB1) ? bsum[t] : 0;
    s[t] = v;
    __syncthreads();
    for (int d = 1; d < 512; d <<= 1) {
        int a = (t >= d) ? s[t - d] : 0;
        __syncthreads();
        s[t] += a;
        __syncthreads();
    }
    if (t < NB1) bsum[t] = s[t] - v;                 // exclusive block offsets
}

__global__ __launch_bounds__(256) void k_scan3(int* __restrict__ off,
                                               const int* __restrict__ bsum,
                                               int* __restrict__ cur) {
    int i = blockIdx.x * 256 + threadIdx.x;
    if (i < NNODES) {
        int o = off[i] + bsum[blockIdx.x];
        off[i] = o;
        cur[i] = o;
    }
}

__global__ __launch_bounds__(256) void k_fill(const int* __restrict__ ei,
                                              int* __restrict__ cur,
                                              int* __restrict__ csr) {
    int e = blockIdx.x * 256 + threadIdx.x;
    int r = ei[e];
    int c = ei[NEDGES + e];
    int p = atomicAdd(&cur[r], 1);
    csr[p] = c;
}

// ---------------- GEMM: out[n][j] = sum_k in[n][k] * W[j][k] + b[j] ----------------
// Block 256 threads. W transposed into 64KB LDS (Wt[k][j]). Each thread owns
// 4 nodes x 4 consecutive j (16 accumulators). x loads are uniform within each
// 32-thread group -> broadcast; Wt reads are conflict-free ds_read_b128.

static __device__ __forceinline__ void fma4(float4& acc, float s, const float4& v) {
    acc.x = fmaf(s, v.x, acc.x);
    acc.y = fmaf(s, v.y, acc.y);
    acc.z = fmaf(s, v.z, acc.z);
    acc.w = fmaf(s, v.w, acc.w);
}

__global__ __launch_bounds__(256) void k_gemm(const float* __restrict__ in,
                                              const float* __restrict__ W,
                                              const float* __restrict__ bias,
                                              float* __restrict__ out,
                                              int nTiles) {
    __shared__ float Wt[D * D];
    int t = threadIdx.x;
    for (int i = t; i < D * D; i += 256) {
        int j = i >> 7, k = i & 127;
        Wt[k * D + j] = W[i];
    }
    int j0 = (t & 31) * 4;
    int ng = t >> 5;  // 0..7 -> node quad within 32-node tile
    float4 b4 = *(const float4*)(bias + j0);
    __syncthreads();

    for (int tile = blockIdx.x; tile < nTiles; tile += gridDim.x) {
        int nb = tile * 32 + ng * 4;
        const float* p0 = in + (size_t)(nb + 0) * D;
        const float* p1 = in + (size_t)(nb + 1) * D;
        const float* p2 = in + (size_t)(nb + 2) * D;
        const float* p3 = in + (size_t)(nb + 3) * D;
        float4 a0 = {0.f, 0.f, 0.f, 0.f};
        float4 a1 = {0.f, 0.f, 0.f, 0.f};
        float4 a2 = {0.f, 0.f, 0.f, 0.f};
        float4 a3 = {0.f, 0.f, 0.f, 0.f};
#pragma unroll 4
        for (int k = 0; k < D; k += 4) {
            float4 w0 = *(const float4*)(Wt + (k + 0) * D + j0);
            float4 w1 = *(const float4*)(Wt + (k + 1) * D + j0);
            float4 w2 = *(const float4*)(Wt + (k + 2) * D + j0);
            float4 w3 = *(const float4*)(Wt + (k + 3) * D + j0);
            float4 x0 = *(const float4*)(p0 + k);
            float4 x1 = *(const float4*)(p1 + k);
            float4 x2 = *(const float4*)(p2 + k);
            float4 x3 = *(const float4*)(p3 + k);
            fma4(a0, x0.x, w0); fma4(a0, x0.y, w1); fma4(a0, x0.z, w2); fma4(a0, x0.w, w3);
            fma4(a1, x1.x, w0); fma4(a1, x1.y, w1); fma4(a1, x1.z, w2); fma4(a1, x1.w, w3);
            fma4(a2, x2.x, w0); fma4(a2, x2.y, w1); fma4(a2, x2.z, w2); fma4(a2, x2.w, w3);
            fma4(a3, x3.x, w0); fma4(a3, x3.y, w1); fma4(a3, x3.z, w2); fma4(a3, x3.w, w3);
        }
        a0.x += b4.x; a0.y += b4.y; a0.z += b4.z; a0.w += b4.w;
        a1.x += b4.x; a1.y += b4.y; a1.z += b4.z; a1.w += b4.w;
        a2.x += b4.x; a2.y += b4.y; a2.z += b4.z; a2.w += b4.w;
        a3.x += b4.x; a3.y += b4.y; a3.z += b4.z; a3.w += b4.w;
        *(float4*)(out + (size_t)(nb + 0) * D + j0) = a0;
        *(float4*)(out + (size_t)(nb + 1) * D + j0) = a1;
        *(float4*)(out + (size_t)(nb + 2) * D + j0) = a2;
        *(float4*)(out + (size_t)(nb + 3) * D + j0) = a3;
    }
}

// ---------------- Message passing: one wave per destination node ----------------
// agg[n][:] = relu( sum_{e in in-edges(n)} h[src(e)][:] ) / max(deg,1)

__global__ __launch_bounds__(256) void k_mp(const float* __restrict__ h,
                                            const int* __restrict__ off,
                                            const int* __restrict__ cnt,
                                            const int* __restrict__ csr,
                                            float* __restrict__ agg) {
    int gid = blockIdx.x * 256 + threadIdx.x;
    int node = gid >> 6;
    int lane = threadIdx.x & 63;
    if (node >= NNODES) return;
    int begin = off[node];
    int c = cnt[node];
    float ax = 0.f, ay = 0.f;
    for (int e = 0; e < c; ++e) {
        int src = csr[begin + e];
        float2 v = *(const float2*)(h + (size_t)src * D + lane * 2);
        ax += v.x;
        ay += v.y;
    }
    float inv = 1.0f / fmaxf((float)c, 1.0f);
    float2 r;
    r.x = fmaxf(ax * inv, 0.f);
    r.y = fmaxf(ay * inv, 0.f);
    *(float2*)(agg + (size_t)node * D + lane * 2) = r;
}

// ---------------- launch ----------------

extern "C" void kernel_launch(void* const* d_in, const int* in_sizes, int n_in,
                              void* d_out, int out_size, void* d_ws, size_t ws_size,
                              hipStream_t stream) {
    const float* x  = (const float*)d_in[0];
    const int*   ei = (const int*)d_in[1];
    const float* W1 = (const float*)d_in[2];
    const float* b1 = (const float*)d_in[3];
    const float* W2 = (const float*)d_in[4];
    const float* b2 = (const float*)d_in[5];
    const float* W3 = (const float*)d_in[6];
    const float* b3 = (const float*)d_in[7];
    float* out = (float*)d_out;

    char* ws = (char*)d_ws;
    int* cnt  = (int*)(ws + 0);
    int* off  = (int*)(ws + (512 << 10));
    int* cur  = (int*)(ws + (1024 << 10));
    int* bsum = (int*)(ws + (1536 << 10));
    int* csr  = (int*)(ws + (2 << 20));
    float* A  = (float*)(ws + ((size_t)8 << 20));   // h0, later agg2
    float* B  = (float*)(ws + ((size_t)64 << 20));  // agg1

    hipMemsetAsync(cnt, 0, NNODES * sizeof(int), stream);
    k_count<<<NEDGES / 256, 256, 0, stream>>>(ei, cnt);
    k_scan1<<<NB1, 256, 0, stream>>>(cnt, off, bsum);
    k_scan2<<<1, 512, 0, stream>>>(bsum);
    k_scan3<<<NB1, 256, 0, stream>>>(off, bsum, cur);
    k_fill<<<NEDGES / 256, 256, 0, stream>>>(ei, cur, csr);

    k_gemm<<<1024, 256, 0, stream>>>(x, W1, b1, A, NNODES / 32);   // h0 = x@W1.T+b1
    k_mp<<<NNODES / 4, 256, 0, stream>>>(A, off, cnt, csr, B);     // agg1 = mp(h0)
    k_gemm<<<1024, 256, 0, stream>>>(B, W2, b2, out, NNODES / 32); // h1b (in d_out)
    k_mp<<<NNODES / 4, 256, 0, stream>>>(out, off, cnt, csr, A);   // agg2 = mp(h1b)
    k_gemm<<<1024, 256, 0, stream>>>(A, W3, b3, out, NNODES / 32); // final
}

// Round 3
// 606.931 us; speedup vs baseline: 1.0489x; 1.0489x over previous
//
#include <hip/hip_runtime.h>

#define NNODES 100000
#define NEDGES 800000
#define D 128
#define NB1 391  // ceil(NNODES/256)

// ---------------- CSR build ----------------

__global__ __launch_bounds__(256) void k_count(const int* __restrict__ ei,
                                               int* __restrict__ cnt) {
    int e = blockIdx.x * 256 + threadIdx.x;          // grid sized exactly E/256
    atomicAdd(&cnt[ei[e]], 1);
}

__global__ __launch_bounds__(256) void k_scan1(const int* __restrict__ cnt,
                                               int* __restrict__ off,
                                               int* __restrict__ bsum) {
    __shared__ int s[256];
    int t = threadIdx.x;
    int i = blockIdx.x * 256 + t;
    int v = (i < NNODES) ? cnt[i] : 0;
    s[t] = v;
    __syncthreads();
    for (int d = 1; d < 256; d <<= 1) {
        int a = (t >= d) ? s[t - d] : 0;
        __syncthreads();
        s[t] += a;
        __syncthreads();
    }
    if (i < NNODES) off[i] = s[t] - v;               // exclusive within block
    if (t == 255) bsum[blockIdx.x] = s[255];         // block total
}

__global__ __launch_bounds__(512) void k_scan2(int* __restrict__ bsum) {
    __shared__ int s[512];
    int t = threadIdx.x;
    int v = (t < NB1) ? bsum[t] : 0;
    s[t] = v;
    __syncthreads();
    for (int d = 1; d < 512; d <<= 1) {
        int a = (t >= d) ? s[t - d] : 0;
        __syncthreads();
        s[t] += a;
        __syncthreads();
    }
    if (t < NB1) bsum[t] = s[t] - v;                 // exclusive block offsets
}

__global__ __launch_bounds__(256) void k_scan3(int* __restrict__ off,
                                               const int* __restrict__ bsum,
                                               int* __restrict__ cur) {
    int i = blockIdx.x * 256 + threadIdx.x;
    if (i < NNODES) {
        int o = off[i] + bsum[blockIdx.x];
        off[i] = o;
        cur[i] = o;
    }
}

__global__ __launch_bounds__(256) void k_fill(const int* __restrict__ ei,
                                              int* __restrict__ cur,
                                              int* __restrict__ csr) {
    int e = blockIdx.x * 256 + threadIdx.x;
    int r = ei[e];
    int c = ei[NEDGES + e];
    int p = atomicAdd(&cur[r], 1);
    csr[p] = c;
}

// ---------------- GEMM: out[n][j] = sum_k in[n][k] * W[j][k] + b[j] ----------------
// Block 512 threads = 64-node tile. W transposed into 64KB LDS with XOR swizzle:
// element (j,k) lives at float-index k*128 + (((j>>2) ^ (k&31))<<2 | (j&3)).
//  - writes: coalesced float4 global load, 4x ds_write_b32 at 8-way conflict (vs 32-way linear)
//  - reads:  ds_read_b128, conflict-free (XOR permutes an already conflict-free pattern)
// Each thread: 4 nodes x 4 j = 16 accumulators. 2 blocks/CU (128KB LDS), 16 waves/CU.

static __device__ __forceinline__ void fma4(float4& acc, float s, const float4& v) {
    acc.x = fmaf(s, v.x, acc.x);
    acc.y = fmaf(s, v.y, acc.y);
    acc.z = fmaf(s, v.z, acc.z);
    acc.w = fmaf(s, v.w, acc.w);
}

static __device__ __forceinline__ int swz(int j, int k) {
    return (k << 7) + ((((j >> 2) ^ (k & 31)) << 2) | (j & 3));
}

__global__ __launch_bounds__(512, 4) void k_gemm(const float* __restrict__ in,
                                                 const float* __restrict__ W,
                                                 const float* __restrict__ bias,
                                                 float* __restrict__ out) {
    __shared__ float Wt[D * D];
    int t = threadIdx.x;
#pragma unroll
    for (int it = 0; it < 8; ++it) {
        int e4 = it * 512 + t;                 // float4 index into W
        float4 w = ((const float4*)W)[e4];
        int e = e4 * 4;
        int j = e >> 7, k = e & 127;           // k..k+3 in row j
        Wt[swz(j, k + 0)] = w.x;
        Wt[swz(j, k + 1)] = w.y;
        Wt[swz(j, k + 2)] = w.z;
        Wt[swz(j, k + 3)] = w.w;
    }
    int jl = t & 31;        // j-group lane: owns j0 = jl*4
    int ng = t >> 5;        // 0..15 -> node quad within 64-node tile
    int j0 = jl * 4;
    float4 b4 = *(const float4*)(bias + j0);
    __syncthreads();

    int nb = blockIdx.x * 64 + ng * 4;
    if (nb >= NNODES) return;
    const float* p0 = in + (size_t)(nb + 0) * D;
    const float* p1 = in + (size_t)(nb + 1) * D;
    const float* p2 = in + (size_t)(nb + 2) * D;
    const float* p3 = in + (size_t)(nb + 3) * D;
    float4 a0 = b4, a1 = b4, a2 = b4, a3 = b4;
#pragma unroll 4
    for (int k = 0; k < D; k += 4) {
        const float4 w0 = *(const float4*)(Wt + swz(j0, k + 0));
        const float4 w1 = *(const float4*)(Wt + swz(j0, k + 1));
        const float4 w2 = *(const float4*)(Wt + swz(j0, k + 2));
        const float4 w3 = *(const float4*)(Wt + swz(j0, k + 3));
        float4 x0 = *(const float4*)(p0 + k);
        float4 x1 = *(const float4*)(p1 + k);
        float4 x2 = *(const float4*)(p2 + k);
        float4 x3 = *(const float4*)(p3 + k);
        fma4(a0, x0.x, w0); fma4(a0, x0.y, w1); fma4(a0, x0.z, w2); fma4(a0, x0.w, w3);
        fma4(a1, x1.x, w0); fma4(a1, x1.y, w1); fma4(a1, x1.z, w2); fma4(a1, x1.w, w3);
        fma4(a2, x2.x, w0); fma4(a2, x2.y, w1); fma4(a2, x2.z, w2); fma4(a2, x2.w, w3);
        fma4(a3, x3.x, w0); fma4(a3, x3.y, w1); fma4(a3, x3.z, w2); fma4(a3, x3.w, w3);
    }
    *(float4*)(out + (size_t)(nb + 0) * D + j0) = a0;
    *(float4*)(out + (size_t)(nb + 1) * D + j0) = a1;
    *(float4*)(out + (size_t)(nb + 2) * D + j0) = a2;
    *(float4*)(out + (size_t)(nb + 3) * D + j0) = a3;
}

// ---------------- Message passing: one wave per destination node ----------------
// agg[n][:] = relu( sum_{e in in-edges(n)} h[src(e)][:] / max(deg,1) )

__global__ __launch_bounds__(256) void k_mp(const float* __restrict__ h,
                                            const int* __restrict__ off,
                                            const int* __restrict__ cnt,
                                            const int* __restrict__ csr,
                                            float* __restrict__ agg) {
    int gid = blockIdx.x * 256 + threadIdx.x;
    int node = gid >> 6;
    int lane = threadIdx.x & 63;
    if (node >= NNODES) return;
    int begin = off[node];
    int c = cnt[node];
    float ax = 0.f, ay = 0.f;
    for (int e = 0; e < c; ++e) {
        int src = csr[begin + e];
        float2 v = *(const float2*)(h + (size_t)src * D + lane * 2);
        ax += v.x;
        ay += v.y;
    }
    float inv = 1.0f / fmaxf((float)c, 1.0f);
    float2 r;
    r.x = fmaxf(ax * inv, 0.f);
    r.y = fmaxf(ay * inv, 0.f);
    *(float2*)(agg + (size_t)node * D + lane * 2) = r;
}

// ---------------- launch ----------------

extern "C" void kernel_launch(void* const* d_in, const int* in_sizes, int n_in,
                              void* d_out, int out_size, void* d_ws, size_t ws_size,
                              hipStream_t stream) {
    const float* x  = (const float*)d_in[0];
    const int*   ei = (const int*)d_in[1];
    const float* W1 = (const float*)d_in[2];
    const float* b1 = (const float*)d_in[3];
    const float* W2 = (const float*)d_in[4];
    const float* b2 = (const float*)d_in[5];
    const float* W3 = (const float*)d_in[6];
    const float* b3 = (const float*)d_in[7];
    float* out = (float*)d_out;

    char* ws = (char*)d_ws;
    int* cnt  = (int*)(ws + 0);
    int* off  = (int*)(ws + (512 << 10));
    int* cur  = (int*)(ws + (1024 << 10));
    int* bsum = (int*)(ws + (1536 << 10));
    int* csr  = (int*)(ws + (2 << 20));
    float* A  = (float*)(ws + ((size_t)8 << 20));   // h0, later agg2
    float* B  = (float*)(ws + ((size_t)64 << 20));  // agg1

    hipMemsetAsync(cnt, 0, NNODES * sizeof(int), stream);
    k_count<<<NEDGES / 256, 256, 0, stream>>>(ei, cnt);
    k_scan1<<<NB1, 256, 0, stream>>>(cnt, off, bsum);
    k_scan2<<<1, 512, 0, stream>>>(bsum);
    k_scan3<<<NB1, 256, 0, stream>>>(off, bsum, cur);
    k_fill<<<NEDGES / 256, 256, 0, stream>>>(ei, cur, csr);

    int gemmGrid = (NNODES + 63) / 64;  // 1563
    k_gemm<<<gemmGrid, 512, 0, stream>>>(x, W1, b1, A);        // h0 = x@W1.T+b1
    k_mp<<<NNODES / 4, 256, 0, stream>>>(A, off, cnt, csr, B); // agg1 = mp(h0)
    k_gemm<<<gemmGrid, 512, 0, stream>>>(B, W2, b2, out);      // h1b (in d_out)
    k_mp<<<NNODES / 4, 256, 0, stream>>>(out, off, cnt, csr, A); // agg2 = mp(h1b)
    k_gemm<<<gemmGrid, 512, 0, stream>>>(A, W3, b3, out);      // final
}